// Round 1
// baseline (1899.040 us; speedup 1.0000x reference)
//
#include <hip/hip_runtime.h>
#include <hip/hip_bf16.h>

typedef __bf16 bf16_t;
typedef __bf16 bf16x2 __attribute__((ext_vector_type(2)));
typedef __bf16 bf16x8 __attribute__((ext_vector_type(8)));
typedef float  f32x2  __attribute__((ext_vector_type(2)));
typedef float  f32x4  __attribute__((ext_vector_type(4)));

#define S_LEN  64
#define BATCH  32
#define HDIM   512
#define VOCAB  32000
#define MROWS  2048      // S*B
#define NGATE  1536      // 3*H
#define LOGITS_ELEMS (65536000)   // 2048*32000

// ---------------------------------------------------------------- utilities

__device__ __forceinline__ float sigm(float x) {
    // NaN-free for any x: exp(+inf)->inf->0, exp(-inf)->0->1
    return 1.f / (1.f + __expf(-x));
}

__device__ __forceinline__ void grid_bar(unsigned int* ctr, unsigned int target) {
    __threadfence();            // agent-scope release of prior global stores
    __syncthreads();
    if (threadIdx.x == 0) {
        __hip_atomic_fetch_add(ctr, 1u, __ATOMIC_RELEASE, __HIP_MEMORY_SCOPE_AGENT);
        while (__hip_atomic_load(ctr, __ATOMIC_ACQUIRE, __HIP_MEMORY_SCOPE_AGENT) < target) {
            __builtin_amdgcn_s_sleep(2);
        }
    }
    __syncthreads();
}

#define GLOAD_LDS16(g, l)                                                        \
    __builtin_amdgcn_global_load_lds(                                            \
        (const __attribute__((address_space(1))) unsigned int*)(g),              \
        (__attribute__((address_space(3))) unsigned int*)(l), 16, 0, 0)

// ---------------------------------------------------------------- embed + split
// x = emb_table[inputs]; write bf16 hi/lo split of x, layout [S*B][512]
__global__ void embed_split(const int* __restrict__ idx, const float* __restrict__ emb,
                            bf16_t* __restrict__ xhi, bf16_t* __restrict__ xlo) {
    int row = blockIdx.x;                 // s*32+b
    int v   = idx[row];
    const float* src = emb + (size_t)v * HDIM;
    int t = threadIdx.x;                  // 256 threads, 2 floats each
    f32x2 f = *(const f32x2*)(src + 2 * t);
    bf16_t h0 = (bf16_t)f[0], h1 = (bf16_t)f[1];
    bf16_t l0 = (bf16_t)(f[0] - (float)h0), l1 = (bf16_t)(f[1] - (float)h1);
    *(bf16x2*)(xhi + (size_t)row * HDIM + 2 * t) = (bf16x2){h0, h1};
    *(bf16x2*)(xlo + (size_t)row * HDIM + 2 * t) = (bf16x2){l0, l1};
}

// ---------------------------------------------------------------- split-bf16 MFMA GEMM
// C[M=2048][N] = A[2048][512] * B[N][512]^T + bias, fp32-accurate via 3-term hi/lo split.
// A pre-split (Ahi/Alo bf16). B fp32, converted during staging.
// Tile 128x128, BK=32, 4 waves (64x64 each), double-buffered 64KB LDS,
// A staged via global_load_lds (linear dest, source-XOR swizzle),
// B reg-staged with T14 split (load-early / ds_write-late), dest-XOR swizzle.
// MODE 0: proj (B/bias selected from 3 gate matrices, N=1536)
// MODE 1: logits (single B/bias, N=32000)
template <int MODE>
__global__ __launch_bounds__(256, 2) void gemm_split(
    const bf16_t* __restrict__ Ahi, const bf16_t* __restrict__ Alo,
    const float* __restrict__ B0, const float* __restrict__ B1, const float* __restrict__ B2,
    const float* __restrict__ bias0, const float* __restrict__ bias1, const float* __restrict__ bias2,
    float* __restrict__ C, int N, int MT) {

    __shared__ bf16_t sA[2][2][128 * 32];   // [buf][hi/lo][row*32+k]  32KB
    __shared__ bf16_t sB[2][2][128 * 32];   // 32KB

    const int tid  = threadIdx.x;
    const int lane = tid & 63;
    const int wv   = tid >> 6;
    const int wg   = blockIdx.x;
    const int tm   = wg % MT;        // consecutive blocks share the B tile (L2 reuse)
    const int tn   = wg / MT;
    const int m0   = tm * 128;
    const int n0   = tn * 128;
    const int wm   = (wv >> 1) * 64;
    const int wn   = (wv & 1) * 64;

    f32x4 br[4][2];                  // B staging regs (waves 2,3)

    auto stageA = [&](int buf, int k0) {
        if (wv < 2) {
            const bf16_t* src = (wv == 0) ? Ahi : Alo;
#pragma unroll
            for (int i = 0; i < 8; ++i) {
                int row = i * 16 + (lane >> 2);
                int ch  = lane & 3;
                int chs = ch ^ (row & 3);                    // source pre-swizzle
                const bf16_t* g = src + (size_t)(m0 + row) * HDIM + k0 + chs * 8;
                GLOAD_LDS16(g, &sA[buf][wv][i * 512]);       // linear dest: base + lane*16
            }
        }
    };

    auto loadB = [&](int t) {
        if (wv >= 2) {
            int k0 = t * 32;
#pragma unroll
            for (int sl = 0; sl < 4; ++sl) {
                int sid = sl * 64 + lane;
                int rl  = (wv - 2) * 64 + (sid >> 2);
                int ch  = sid & 3;
                int n   = n0 + rl;
                const float* bp;
                if (MODE == 0) {
                    bp = (n < 512)  ? (B0 + (size_t)n * HDIM)
                       : (n < 1024) ? (B1 + (size_t)(n - 512) * HDIM)
                                    : (B2 + (size_t)(n - 1024) * HDIM);
                } else {
                    bp = B0 + (size_t)n * HDIM;
                }
                br[sl][0] = *(const f32x4*)(bp + k0 + ch * 8);
                br[sl][1] = *(const f32x4*)(bp + k0 + ch * 8 + 4);
            }
        }
    };

    auto writeB = [&](int buf) {
        if (wv >= 2) {
#pragma unroll
            for (int sl = 0; sl < 4; ++sl) {
                int sid = sl * 64 + lane;
                int rl  = (wv - 2) * 64 + (sid >> 2);
                int ch  = sid & 3;
                int chs = ch ^ (rl & 3);                     // dest swizzle (reg-staged)
                bf16x8 vh, vl;
#pragma unroll
                for (int e = 0; e < 8; ++e) {
                    float f = (e < 4) ? br[sl][0][e] : br[sl][1][e - 4];
                    bf16_t h = (bf16_t)f;
                    vh[e] = h;
                    vl[e] = (bf16_t)(f - (float)h);
                }
                *(bf16x8*)&sB[buf][0][rl * 32 + chs * 8] = vh;
                *(bf16x8*)&sB[buf][1][rl * 32 + chs * 8] = vl;
            }
        }
    };

    f32x4 acc[4][4];
#pragma unroll
    for (int i = 0; i < 4; ++i)
#pragma unroll
        for (int j = 0; j < 4; ++j) acc[i][j] = (f32x4){0.f, 0.f, 0.f, 0.f};

    auto mfmaPhase = [&](int buf) {
        bf16x8 ah[4], al[4], bh[4], bl[4];
#pragma unroll
        for (int mt = 0; mt < 4; ++mt) {
            int ml  = wm + mt * 16 + (lane & 15);
            int chs = (lane >> 4) ^ (ml & 3);
            ah[mt] = *(const bf16x8*)&sA[buf][0][ml * 32 + chs * 8];
            al[mt] = *(const bf16x8*)&sA[buf][1][ml * 32 + chs * 8];
        }
#pragma unroll
        for (int nt = 0; nt < 4; ++nt) {
            int nl  = wn + nt * 16 + (lane & 15);
            int chs = (lane >> 4) ^ (nl & 3);
            bh[nt] = *(const bf16x8*)&sB[buf][0][nl * 32 + chs * 8];
            bl[nt] = *(const bf16x8*)&sB[buf][1][nl * 32 + chs * 8];
        }
#pragma unroll
        for (int mt = 0; mt < 4; ++mt)
#pragma unroll
            for (int nt = 0; nt < 4; ++nt) {
                acc[mt][nt] = __builtin_amdgcn_mfma_f32_16x16x32_bf16(ah[mt], bh[nt], acc[mt][nt], 0, 0, 0);
                acc[mt][nt] = __builtin_amdgcn_mfma_f32_16x16x32_bf16(ah[mt], bl[nt], acc[mt][nt], 0, 0, 0);
                acc[mt][nt] = __builtin_amdgcn_mfma_f32_16x16x32_bf16(al[mt], bh[nt], acc[mt][nt], 0, 0, 0);
            }
    };

    // prologue
    stageA(0, 0);
    loadB(0);
    writeB(0);
    asm volatile("s_waitcnt vmcnt(0)" ::: "memory");
    __syncthreads();

#pragma unroll 2
    for (int t = 0; t < 16; ++t) {
        int cur = t & 1;
        int nxt = cur ^ 1;
        if (t + 1 < 16) { stageA(nxt, (t + 1) * 32); loadB(t + 1); }  // async issue
        mfmaPhase(cur);
        if (t + 1 < 16) writeB(nxt);                                  // write-late (T14)
        asm volatile("s_waitcnt vmcnt(0)" ::: "memory");
        __syncthreads();
    }

    // epilogue: bias + store
    float bv[4];
#pragma unroll
    for (int nt = 0; nt < 4; ++nt) {
        int col = n0 + wn + nt * 16 + (lane & 15);
        if (MODE == 0) {
            int g = col >> 9, d = col & 511;
            const float* bb = (g == 0) ? bias0 : (g == 1) ? bias1 : bias2;
            bv[nt] = bb[d];
        } else {
            bv[nt] = bias0[col];
        }
    }
#pragma unroll
    for (int mt = 0; mt < 4; ++mt)
#pragma unroll
        for (int nt = 0; nt < 4; ++nt) {
            int col = n0 + wn + nt * 16 + (lane & 15);
#pragma unroll
            for (int r = 0; r < 4; ++r) {
                int row = m0 + wm + mt * 16 + (lane >> 4) * 4 + r;
                C[(size_t)row * N + col] = acc[mt][nt][r] + bv[nt];
            }
        }
}

// ---------------------------------------------------------------- GRU recurrent scan
// Persistent cooperative kernel: 32 WGs x 256. WG owns 16 output dims (all 3 gates);
// waves split K 4-way (128 each). Recurrent weights live split-bf16 in REGISTERS
// (loaded once, reused 64 steps). h exchanged via global bf16 hi/lo buffers with an
// agent-scope atomic grid barrier per step (XCD-safe release/acquire).
__global__ void gru_scan(
    const float* __restrict__ xg,                         // [2048][1536] input projections
    const float* __restrict__ Wr, const float* __restrict__ Wz, const float* __restrict__ Wh,
    const float* __restrict__ h0,                         // [32][512]
    bf16_t* __restrict__ hs_hi, bf16_t* __restrict__ hs_lo,  // [2048][512] seq output
    bf16_t* __restrict__ h_hi,  bf16_t* __restrict__ h_lo,   // [32][512] state
    float* __restrict__ hfin,                             // [32][512] final state out
    unsigned int* __restrict__ ctr) {

    __shared__ float red[12][32][16];   // [q*3+g][b][dloc] K-split partials
    __shared__ float hown[32][16];      // this WG's fp32 state slice

    const int tid  = threadIdx.x;
    const int lane = tid & 63;
    const int q    = tid >> 6;              // wave -> K-quarter
    const int D0   = blockIdx.x * 16;       // dim slice
    const int kb   = q * 128;
    const int colD = D0 + (lane & 15);      // B-operand row (output dim)
    const int krow = kb + (lane >> 4) * 8;  // fragment k base

    // persistent recurrent-weight fragments: [gate][kt] hi/lo (96 VGPR)
    bf16x8 Bh[3][4], Bl[3][4];
#pragma unroll
    for (int g = 0; g < 3; ++g) {
        const float* W = (g == 0) ? Wr : (g == 1) ? Wz : Wh;
#pragma unroll
        for (int kt = 0; kt < 4; ++kt) {
            const float* p = W + (size_t)colD * HDIM + krow + kt * 32;
            f32x4 f0 = *(const f32x4*)p;
            f32x4 f1 = *(const f32x4*)(p + 4);
            bf16x8 vh, vl;
#pragma unroll
            for (int e = 0; e < 8; ++e) {
                float f = (e < 4) ? f0[e] : f1[e - 4];
                bf16_t h = (bf16_t)f;
                vh[e] = h;
                vl[e] = (bf16_t)(f - (float)h);
            }
            Bh[g][kt] = vh; Bl[g][kt] = vl;
        }
    }

    unsigned int ep = 0;

    // init state (h0) + publish split state
    for (int p = tid; p < 512; p += 256) {
        int b = p >> 4, dl = p & 15;
        float v = h0[b * HDIM + D0 + dl];
        hown[b][dl] = v;
        bf16_t hh = (bf16_t)v;
        h_hi[b * HDIM + D0 + dl] = hh;
        h_lo[b * HDIM + D0 + dl] = (bf16_t)(v - (float)hh);
    }
    ++ep; grid_bar(ctr, 32u * ep);

#pragma unroll 1
    for (int s = 0; s < S_LEN; ++s) {
        // A fragments: full h (hi/lo) for this wave's K-quarter
        bf16x8 Ah[2][4], Al[2][4];
#pragma unroll
        for (int mt = 0; mt < 2; ++mt)
#pragma unroll
            for (int kt = 0; kt < 4; ++kt) {
                size_t off = (size_t)(mt * 16 + (lane & 15)) * HDIM + krow + kt * 32;
                Ah[mt][kt] = *(const bf16x8*)(h_hi + off);
                Al[mt][kt] = *(const bf16x8*)(h_lo + off);
            }
        f32x4 acc[3][2];
#pragma unroll
        for (int g = 0; g < 3; ++g)
#pragma unroll
            for (int mt = 0; mt < 2; ++mt) acc[g][mt] = (f32x4){0.f, 0.f, 0.f, 0.f};
#pragma unroll
        for (int kt = 0; kt < 4; ++kt)
#pragma unroll
            for (int g = 0; g < 3; ++g)
#pragma unroll
                for (int mt = 0; mt < 2; ++mt) {
                    acc[g][mt] = __builtin_amdgcn_mfma_f32_16x16x32_bf16(Ah[mt][kt], Bh[g][kt], acc[g][mt], 0, 0, 0);
                    acc[g][mt] = __builtin_amdgcn_mfma_f32_16x16x32_bf16(Ah[mt][kt], Bl[g][kt], acc[g][mt], 0, 0, 0);
                    acc[g][mt] = __builtin_amdgcn_mfma_f32_16x16x32_bf16(Al[mt][kt], Bh[g][kt], acc[g][mt], 0, 0, 0);
                }
        // dump K-partials
#pragma unroll
        for (int g = 0; g < 3; ++g)
#pragma unroll
            for (int mt = 0; mt < 2; ++mt)
#pragma unroll
                for (int r = 0; r < 4; ++r)
                    red[q * 3 + g][mt * 16 + (lane >> 4) * 4 + r][lane & 15] = acc[g][mt][r];
        __syncthreads();

        // elementwise GRU cell on (b, dim) pairs
        for (int p = tid; p < 512; p += 256) {
            int b = p >> 4, dl = p & 15;
            float vr = red[0][b][dl] + red[3][b][dl] + red[6][b][dl] + red[9][b][dl];
            float vz = red[1][b][dl] + red[4][b][dl] + red[7][b][dl] + red[10][b][dl];
            float vh = red[2][b][dl] + red[5][b][dl] + red[8][b][dl] + red[11][b][dl];
            int row = s * BATCH + b;
            const float* xp = xg + (size_t)row * NGATE + D0 + dl;
            float xr = xp[0], xz = xp[512], xh = xp[1024];
            float hp = hown[b][dl];
            float r  = sigm(xr + vr);
            float z  = sigm(xz + vz);
            float hc = 2.f * sigm(2.f * (xh + r * vh)) - 1.f;   // tanh, NaN-free
            float hn = (1.f - z) * hc + z * hp;
            hown[b][dl] = hn;
            bf16_t hh = (bf16_t)hn;
            bf16_t hl = (bf16_t)(hn - (float)hh);
            int gi = b * HDIM + D0 + dl;
            h_hi[gi] = hh; h_lo[gi] = hl;
            size_t so = (size_t)row * HDIM + D0 + dl;
            hs_hi[so] = hh; hs_lo[so] = hl;
            if (s == S_LEN - 1) hfin[gi] = hn;
        }
        ++ep; grid_bar(ctr, 32u * ep);
    }
}

// ---------------------------------------------------------------- launch

extern "C" void kernel_launch(void* const* d_in, const int* in_sizes, int n_in,
                              void* d_out, int out_size, void* d_ws, size_t ws_size,
                              hipStream_t stream) {
    const int*   idx  = (const int*)  d_in[0];
    const float* hid  = (const float*)d_in[1];
    const float* emb  = (const float*)d_in[2];
    const float* Wir  = (const float*)d_in[3];
    const float* bir  = (const float*)d_in[4];
    const float* Wiz  = (const float*)d_in[5];
    const float* biz  = (const float*)d_in[6];
    const float* Wih  = (const float*)d_in[7];
    const float* bih  = (const float*)d_in[8];
    const float* Whr  = (const float*)d_in[9];
    const float* Whz  = (const float*)d_in[10];
    const float* Whh  = (const float*)d_in[11];
    const float* Wout = (const float*)d_in[12];
    const float* bout = (const float*)d_in[13];
    float* out = (float*)d_out;

    char* w = (char*)d_ws;
    unsigned int* ctr0 = (unsigned int*)w;          // zeroed each launch
    unsigned int* ctr1 = ctr0 + 1;
    bf16_t* x_hi   = (bf16_t*)(w + 256);
    bf16_t* x_lo   = x_hi   + (size_t)MROWS * HDIM;
    bf16_t* hs1_hi = x_lo   + (size_t)MROWS * HDIM;
    bf16_t* hs1_lo = hs1_hi + (size_t)MROWS * HDIM;
    bf16_t* hs2_hi = hs1_lo + (size_t)MROWS * HDIM;
    bf16_t* hs2_lo = hs2_hi + (size_t)MROWS * HDIM;
    bf16_t* hh_buf = hs2_lo + (size_t)MROWS * HDIM;
    bf16_t* hl_buf = hh_buf + BATCH * HDIM;
    float*  xg     = (float*)(hl_buf + BATCH * HDIM);

    const int WHE = HDIM * HDIM;   // per-layer weight stride

    hipMemsetAsync(d_ws, 0, 256, stream);

    embed_split<<<MROWS, 256, 0, stream>>>(idx, emb, x_hi, x_lo);

    // layer 1
    gemm_split<0><<<16 * 12, 256, 0, stream>>>(x_hi, x_lo, Wir, Wiz, Wih,
                                               bir, biz, bih, xg, NGATE, 16);
    gru_scan<<<32, 256, 0, stream>>>(xg, Whr, Whz, Whh, hid,
                                     hs1_hi, hs1_lo, hh_buf, hl_buf,
                                     out + LOGITS_ELEMS, ctr0);
    // layer 2
    gemm_split<0><<<16 * 12, 256, 0, stream>>>(hs1_hi, hs1_lo, Wir + WHE, Wiz + WHE, Wih + WHE,
                                               bir + HDIM, biz + HDIM, bih + HDIM, xg, NGATE, 16);
    gru_scan<<<32, 256, 0, stream>>>(xg, Whr + WHE, Whz + WHE, Whh + WHE, hid + BATCH * HDIM,
                                     hs2_hi, hs2_lo, hh_buf, hl_buf,
                                     out + LOGITS_ELEMS + BATCH * HDIM, ctr1);
    // logits
    gemm_split<1><<<16 * 250, 256, 0, stream>>>(hs2_hi, hs2_lo, Wout, nullptr, nullptr,
                                                bout, nullptr, nullptr, out, VOCAB, 16);
}

// Round 4
// 1297.205 us; speedup vs baseline: 1.4639x; 1.4639x over previous
//
#include <hip/hip_runtime.h>
#include <hip/hip_bf16.h>

typedef __bf16 bf16_t;
typedef __bf16 bf16x2 __attribute__((ext_vector_type(2)));
typedef __bf16 bf16x8 __attribute__((ext_vector_type(8)));
typedef float  f32x2  __attribute__((ext_vector_type(2)));
typedef float  f32x4  __attribute__((ext_vector_type(4)));
typedef unsigned int u32;
typedef unsigned int u32x4 __attribute__((ext_vector_type(4)));

#define S_LEN  64
#define BATCH  32
#define HDIM   512
#define VOCAB  32000
#define MROWS  2048      // S*B
#define NGATE  1536      // 3*H
#define LOGITS_ELEMS (65536000)   // 2048*32000

// ---------------------------------------------------------------- utilities

__device__ __forceinline__ float sigm(float x) {
    return 1.f / (1.f + __expf(-x));   // NaN-free for any finite/inf x
}

// system-coherent (bypass L1/L2, reach fabric coherence point) accesses
__device__ __forceinline__ void st_sys_u32(u32* p, u32 v) {
    asm volatile("global_store_dword %0, %1, off sc0 sc1" :: "v"(p), "v"(v) : "memory");
}
__device__ __forceinline__ u32x4 ld_sys_u32x4(const u32* p) {
    u32x4 r;
    asm volatile("global_load_dwordx4 %0, %1, off sc0 sc1" : "=v"(r) : "v"(p) : "memory");
    return r;   // NOTE: caller must s_waitcnt vmcnt(0) before use
}

#define GLOAD_LDS16(g, l)                                                        \
    __builtin_amdgcn_global_load_lds(                                            \
        (const __attribute__((address_space(1))) unsigned int*)(g),              \
        (__attribute__((address_space(3))) unsigned int*)(l), 16, 0, 0)

// ---------------------------------------------------------------- embed + split
__global__ void embed_split(const int* __restrict__ idx, const float* __restrict__ emb,
                            bf16_t* __restrict__ xhi, bf16_t* __restrict__ xlo) {
    int row = blockIdx.x;
    int v   = idx[row];
    const float* src = emb + (size_t)v * HDIM;
    int t = threadIdx.x;
    f32x2 f = *(const f32x2*)(src + 2 * t);
    bf16_t h0 = (bf16_t)f[0], h1 = (bf16_t)f[1];
    bf16_t l0 = (bf16_t)(f[0] - (float)h0), l1 = (bf16_t)(f[1] - (float)h1);
    *(bf16x2*)(xhi + (size_t)row * HDIM + 2 * t) = (bf16x2){h0, h1};
    *(bf16x2*)(xlo + (size_t)row * HDIM + 2 * t) = (bf16x2){l0, l1};
}

// ---------------------------------------------------------------- split-bf16 MFMA GEMM
// (unchanged structure from R1; added XCD-bijective block swizzle)
template <int MODE>
__global__ __launch_bounds__(256, 2) void gemm_split(
    const bf16_t* __restrict__ Ahi, const bf16_t* __restrict__ Alo,
    const float* __restrict__ B0, const float* __restrict__ B1, const float* __restrict__ B2,
    const float* __restrict__ bias0, const float* __restrict__ bias1, const float* __restrict__ bias2,
    float* __restrict__ C, int N, int MT) {

    __shared__ bf16_t sA[2][2][128 * 32];
    __shared__ bf16_t sB[2][2][128 * 32];

    const int tid  = threadIdx.x;
    const int lane = tid & 63;
    const int wv   = tid >> 6;
    // XCD-bijective swizzle: grid % 8 == 0 guaranteed by launch; keeps the MT
    // consecutive M-tiles (which share one B panel) on a single XCD's L2.
    const int wg   = (blockIdx.x & 7) * ((int)gridDim.x >> 3) + (blockIdx.x >> 3);
    const int tm   = wg % MT;
    const int tn   = wg / MT;
    const int m0   = tm * 128;
    const int n0   = tn * 128;
    const int wm   = (wv >> 1) * 64;
    const int wn   = (wv & 1) * 64;

    f32x4 br[4][2];

    auto stageA = [&](int buf, int k0) {
        if (wv < 2) {
            const bf16_t* src = (wv == 0) ? Ahi : Alo;
#pragma unroll
            for (int i = 0; i < 8; ++i) {
                int row = i * 16 + (lane >> 2);
                int ch  = lane & 3;
                int chs = ch ^ (row & 3);
                const bf16_t* g = src + (size_t)(m0 + row) * HDIM + k0 + chs * 8;
                GLOAD_LDS16(g, &sA[buf][wv][i * 512]);
            }
        }
    };

    auto loadB = [&](int t) {
        if (wv >= 2) {
            int k0 = t * 32;
#pragma unroll
            for (int sl = 0; sl < 4; ++sl) {
                int sid = sl * 64 + lane;
                int rl  = (wv - 2) * 64 + (sid >> 2);
                int ch  = sid & 3;
                int n   = n0 + rl;
                const float* bp;
                if (MODE == 0) {
                    bp = (n < 512)  ? (B0 + (size_t)n * HDIM)
                       : (n < 1024) ? (B1 + (size_t)(n - 512) * HDIM)
                                    : (B2 + (size_t)(n - 1024) * HDIM);
                } else {
                    bp = B0 + (size_t)n * HDIM;
                }
                br[sl][0] = *(const f32x4*)(bp + k0 + ch * 8);
                br[sl][1] = *(const f32x4*)(bp + k0 + ch * 8 + 4);
            }
        }
    };

    auto writeB = [&](int buf) {
        if (wv >= 2) {
#pragma unroll
            for (int sl = 0; sl < 4; ++sl) {
                int sid = sl * 64 + lane;
                int rl  = (wv - 2) * 64 + (sid >> 2);
                int ch  = sid & 3;
                int chs = ch ^ (rl & 3);
                bf16x8 vh, vl;
#pragma unroll
                for (int e = 0; e < 8; ++e) {
                    float f = (e < 4) ? br[sl][0][e] : br[sl][1][e - 4];
                    bf16_t h = (bf16_t)f;
                    vh[e] = h;
                    vl[e] = (bf16_t)(f - (float)h);
                }
                *(bf16x8*)&sB[buf][0][rl * 32 + chs * 8] = vh;
                *(bf16x8*)&sB[buf][1][rl * 32 + chs * 8] = vl;
            }
        }
    };

    f32x4 acc[4][4];
#pragma unroll
    for (int i = 0; i < 4; ++i)
#pragma unroll
        for (int j = 0; j < 4; ++j) acc[i][j] = (f32x4){0.f, 0.f, 0.f, 0.f};

    auto mfmaPhase = [&](int buf) {
        bf16x8 ah[4], al[4], bh[4], bl[4];
#pragma unroll
        for (int mt = 0; mt < 4; ++mt) {
            int ml  = wm + mt * 16 + (lane & 15);
            int chs = (lane >> 4) ^ (ml & 3);
            ah[mt] = *(const bf16x8*)&sA[buf][0][ml * 32 + chs * 8];
            al[mt] = *(const bf16x8*)&sA[buf][1][ml * 32 + chs * 8];
        }
#pragma unroll
        for (int nt = 0; nt < 4; ++nt) {
            int nl  = wn + nt * 16 + (lane & 15);
            int chs = (lane >> 4) ^ (nl & 3);
            bh[nt] = *(const bf16x8*)&sB[buf][0][nl * 32 + chs * 8];
            bl[nt] = *(const bf16x8*)&sB[buf][1][nl * 32 + chs * 8];
        }
#pragma unroll
        for (int mt = 0; mt < 4; ++mt)
#pragma unroll
            for (int nt = 0; nt < 4; ++nt) {
                acc[mt][nt] = __builtin_amdgcn_mfma_f32_16x16x32_bf16(ah[mt], bh[nt], acc[mt][nt], 0, 0, 0);
                acc[mt][nt] = __builtin_amdgcn_mfma_f32_16x16x32_bf16(ah[mt], bl[nt], acc[mt][nt], 0, 0, 0);
                acc[mt][nt] = __builtin_amdgcn_mfma_f32_16x16x32_bf16(al[mt], bh[nt], acc[mt][nt], 0, 0, 0);
            }
    };

    stageA(0, 0);
    loadB(0);
    writeB(0);
    asm volatile("s_waitcnt vmcnt(0)" ::: "memory");
    __syncthreads();

#pragma unroll 2
    for (int t = 0; t < 16; ++t) {
        int cur = t & 1;
        int nxt = cur ^ 1;
        if (t + 1 < 16) { stageA(nxt, (t + 1) * 32); loadB(t + 1); }
        mfmaPhase(cur);
        if (t + 1 < 16) writeB(nxt);
        asm volatile("s_waitcnt vmcnt(0)" ::: "memory");
        __syncthreads();
    }

    float bv[4];
#pragma unroll
    for (int nt = 0; nt < 4; ++nt) {
        int col = n0 + wn + nt * 16 + (lane & 15);
        if (MODE == 0) {
            int g = col >> 9, d = col & 511;
            const float* bb = (g == 0) ? bias0 : (g == 1) ? bias1 : bias2;
            bv[nt] = bb[d];
        } else {
            bv[nt] = bias0[col];
        }
    }
#pragma unroll
    for (int mt = 0; mt < 4; ++mt)
#pragma unroll
        for (int nt = 0; nt < 4; ++nt) {
            int col = n0 + wn + nt * 16 + (lane & 15);
#pragma unroll
            for (int r = 0; r < 4; ++r) {
                int row = m0 + wm + mt * 16 + (lane >> 4) * 4 + r;
                C[(size_t)row * N + col] = acc[mt][nt][r] + bv[nt];
            }
        }
}

// ---------------------------------------------------------------- GRU recurrent scan
// 32 persistent WGs x 256. WG owns 16 output dims (all 3 gates); waves split K 4-way.
// Weights: split-bf16 in LDS (fragment-contiguous, per-wave slices -> no cross-wave sync).
// h state: double-buffered packed u32 (hi|lo<<16) in global, exchanged with sc0/sc1
// write-through stores + bypass loads (no cache maintenance). Barrier: per-WG epoch
// flags, relaxed agent-scope atomics, polled by wave 0.
__global__ __launch_bounds__(256, 1) void gru_scan(
    const float* __restrict__ xg,
    const float* __restrict__ Wr, const float* __restrict__ Wz, const float* __restrict__ Wh,
    const float* __restrict__ h0,
    bf16_t* __restrict__ hs_hi, bf16_t* __restrict__ hs_lo,
    u32* __restrict__ hpk,        // [2][32*512] packed state, double-buffered
    float* __restrict__ hfin,
    u32* __restrict__ flags) {    // [32], zeroed before launch

    __shared__ bf16_t sW[3][4][4][2][512];   // [gate][q][kt][hi/lo][lane*8]  96KB
    __shared__ float red[12][32][16];        // 24KB
    __shared__ float hown[32][16];           // 2KB

    const int tid  = threadIdx.x;
    const int lane = tid & 63;
    const int q    = tid >> 6;
    const int wg   = blockIdx.x;
    const int D0   = wg * 16;
    const int colD = D0 + (lane & 15);
    const int krow = q * 128 + (lane >> 4) * 8;

    // ---- split weights into LDS fragments (each wave writes+reads only its q slice)
#pragma unroll
    for (int g = 0; g < 3; ++g) {
        const float* W = (g == 0) ? Wr : (g == 1) ? Wz : Wh;
#pragma unroll
        for (int kt = 0; kt < 4; ++kt) {
            const float* p = W + (size_t)colD * HDIM + krow + kt * 32;
            f32x4 f0 = *(const f32x4*)p;
            f32x4 f1 = *(const f32x4*)(p + 4);
            bf16x8 vh, vl;
#pragma unroll
            for (int e = 0; e < 8; ++e) {
                float f = (e < 4) ? f0[e] : f1[e - 4];
                bf16_t h = (bf16_t)f;
                vh[e] = h;
                vl[e] = (bf16_t)(f - (float)h);
            }
            *(bf16x8*)&sW[g][q][kt][0][lane * 8] = vh;
            *(bf16x8*)&sW[g][q][kt][1][lane * 8] = vl;
        }
    }

    // ---- init state (buffer 0) + publish
#pragma unroll
    for (int rnd = 0; rnd < 2; ++rnd) {
        int p = tid + rnd * 256;
        int b = p >> 4, dl = p & 15;
        float v = h0[b * HDIM + D0 + dl];
        hown[b][dl] = v;
        bf16_t hh = (bf16_t)v;
        bf16_t hl = (bf16_t)(v - (float)hh);
        u32 pk = (u32)__builtin_bit_cast(unsigned short, hh) |
                 ((u32)__builtin_bit_cast(unsigned short, hl) << 16);
        st_sys_u32(&hpk[b * 512 + D0 + dl], pk);
    }

    u32 ep = 0;
    // ---- barrier lambda: drain stores, flag, poll
    auto scan_bar = [&]() {
        ++ep;
        asm volatile("s_waitcnt vmcnt(0)" ::: "memory");
        __syncthreads();
        if (tid == 0)
            __hip_atomic_store(&flags[wg], ep, __ATOMIC_RELAXED, __HIP_MEMORY_SCOPE_AGENT);
        if (tid < 32) {
            int it = 0;
            while (__hip_atomic_load(&flags[tid], __ATOMIC_RELAXED, __HIP_MEMORY_SCOPE_AGENT) < ep) {
                __builtin_amdgcn_s_sleep(1);
                if (++it > (1 << 20)) break;   // fail visibly instead of hanging
            }
        }
        __syncthreads();
    };

    scan_bar();

    for (int s = 0; s < S_LEN; ++s) {
        const u32* hc = hpk + (s & 1) * (BATCH * 512);
        u32*       hn = hpk + ((s + 1) & 1) * (BATCH * 512);

        // prefetch xg for the cell phase (independent of h)
        float xr[2], xz[2], xh[2];
#pragma unroll
        for (int rnd = 0; rnd < 2; ++rnd) {
            int p = tid + rnd * 256;
            int b = p >> 4, dl = p & 15;
            const float* xp = xg + (size_t)(s * BATCH + b) * NGATE + D0 + dl;
            xr[rnd] = xp[0]; xz[rnd] = xp[512]; xh[rnd] = xp[1024];
        }

        // issue all 16 h-fragment loads (bypass caches), then drain once
        u32x4 w[2][4][2];
#pragma unroll
        for (int mt = 0; mt < 2; ++mt)
#pragma unroll
            for (int kt = 0; kt < 4; ++kt) {
                const u32* p = hc + (mt * 16 + (lane & 15)) * 512 + krow + kt * 32;
                w[mt][kt][0] = ld_sys_u32x4(p);
                w[mt][kt][1] = ld_sys_u32x4(p + 4);
            }
        asm volatile("s_waitcnt vmcnt(0)" ::: "memory");
        __builtin_amdgcn_sched_barrier(0);

        f32x4 acc[3][2];
#pragma unroll
        for (int g = 0; g < 3; ++g)
#pragma unroll
            for (int mt = 0; mt < 2; ++mt) acc[g][mt] = (f32x4){0.f, 0.f, 0.f, 0.f};

#pragma unroll
        for (int kt = 0; kt < 4; ++kt) {
            bf16x8 Ahf[2], Alf[2];
#pragma unroll
            for (int mt = 0; mt < 2; ++mt) {
                u32x4 wa = w[mt][kt][0], wb = w[mt][kt][1];
                u32x4 hiw, low;
                hiw[0] = (wa[0] & 0xffffu) | (wa[1] << 16);
                hiw[1] = (wa[2] & 0xffffu) | (wa[3] << 16);
                hiw[2] = (wb[0] & 0xffffu) | (wb[1] << 16);
                hiw[3] = (wb[2] & 0xffffu) | (wb[3] << 16);
                low[0] = (wa[0] >> 16) | (wa[1] & 0xffff0000u);
                low[1] = (wa[2] >> 16) | (wa[3] & 0xffff0000u);
                low[2] = (wb[0] >> 16) | (wb[1] & 0xffff0000u);
                low[3] = (wb[2] >> 16) | (wb[3] & 0xffff0000u);
                Ahf[mt] = __builtin_bit_cast(bf16x8, hiw);
                Alf[mt] = __builtin_bit_cast(bf16x8, low);
            }
#pragma unroll
            for (int g = 0; g < 3; ++g) {
                bf16x8 Bhf = *(const bf16x8*)&sW[g][q][kt][0][lane * 8];
                bf16x8 Blf = *(const bf16x8*)&sW[g][q][kt][1][lane * 8];
#pragma unroll
                for (int mt = 0; mt < 2; ++mt) {
                    acc[g][mt] = __builtin_amdgcn_mfma_f32_16x16x32_bf16(Ahf[mt], Bhf, acc[g][mt], 0, 0, 0);
                    acc[g][mt] = __builtin_amdgcn_mfma_f32_16x16x32_bf16(Ahf[mt], Blf, acc[g][mt], 0, 0, 0);
                    acc[g][mt] = __builtin_amdgcn_mfma_f32_16x16x32_bf16(Alf[mt], Bhf, acc[g][mt], 0, 0, 0);
                }
            }
        }

        // K-partials -> LDS
#pragma unroll
        for (int g = 0; g < 3; ++g)
#pragma unroll
            for (int mt = 0; mt < 2; ++mt)
#pragma unroll
                for (int r = 0; r < 4; ++r)
                    red[q * 3 + g][mt * 16 + (lane >> 4) * 4 + r][lane & 15] = acc[g][mt][r];
        __syncthreads();

        // elementwise cell
#pragma unroll
        for (int rnd = 0; rnd < 2; ++rnd) {
            int p = tid + rnd * 256;
            int b = p >> 4, dl = p & 15;
            float vr = red[0][b][dl] + red[3][b][dl] + red[6][b][dl] + red[9][b][dl];
            float vz = red[1][b][dl] + red[4][b][dl] + red[7][b][dl] + red[10][b][dl];
            float vh = red[2][b][dl] + red[5][b][dl] + red[8][b][dl] + red[11][b][dl];
            float hp = hown[b][dl];
            float r  = sigm(xr[rnd] + vr);
            float z  = sigm(xz[rnd] + vz);
            float hcand = 2.f * sigm(2.f * (xh[rnd] + r * vh)) - 1.f;
            float hnv = (1.f - z) * hcand + z * hp;
            hown[b][dl] = hnv;
            bf16_t hh = (bf16_t)hnv;
            bf16_t hl = (bf16_t)(hnv - (float)hh);
            u32 pk = (u32)__builtin_bit_cast(unsigned short, hh) |
                     ((u32)__builtin_bit_cast(unsigned short, hl) << 16);
            st_sys_u32(&hn[b * 512 + D0 + dl], pk);
            int row = s * BATCH + b;
            size_t so = (size_t)row * HDIM + D0 + dl;
            hs_hi[so] = hh; hs_lo[so] = hl;
            if (s == S_LEN - 1) hfin[b * HDIM + D0 + dl] = hnv;
        }
        scan_bar();
    }
}

// ---------------------------------------------------------------- launch

extern "C" void kernel_launch(void* const* d_in, const int* in_sizes, int n_in,
                              void* d_out, int out_size, void* d_ws, size_t ws_size,
                              hipStream_t stream) {
    const int*   idx  = (const int*)  d_in[0];
    const float* hid  = (const float*)d_in[1];
    const float* emb  = (const float*)d_in[2];
    const float* Wir  = (const float*)d_in[3];
    const float* bir  = (const float*)d_in[4];
    const float* Wiz  = (const float*)d_in[5];
    const float* biz  = (const float*)d_in[6];
    const float* Wih  = (const float*)d_in[7];
    const float* bih  = (const float*)d_in[8];
    const float* Whr  = (const float*)d_in[9];
    const float* Whz  = (const float*)d_in[10];
    const float* Whh  = (const float*)d_in[11];
    const float* Wout = (const float*)d_in[12];
    const float* bout = (const float*)d_in[13];
    float* out = (float*)d_out;

    char* w = (char*)d_ws;
    u32* flags0 = (u32*)w;                          // 128B
    u32* flags1 = (u32*)(w + 128);                  // 128B
    u32* hpk    = (u32*)(w + 512);                  // 2*32*512*4 = 128KB
    bf16_t* x_hi   = (bf16_t*)(w + 512 + 131072);
    bf16_t* x_lo   = x_hi   + (size_t)MROWS * HDIM;
    bf16_t* hs1_hi = x_lo   + (size_t)MROWS * HDIM;
    bf16_t* hs1_lo = hs1_hi + (size_t)MROWS * HDIM;
    bf16_t* hs2_hi = hs1_lo + (size_t)MROWS * HDIM;
    bf16_t* hs2_lo = hs2_hi + (size_t)MROWS * HDIM;
    float*  xg     = (float*)(hs2_lo + (size_t)MROWS * HDIM);

    const int WHE = HDIM * HDIM;

    hipMemsetAsync(d_ws, 0, 512, stream);

    embed_split<<<MROWS, 256, 0, stream>>>(idx, emb, x_hi, x_lo);

    // layer 1
    gemm_split<0><<<16 * 12, 256, 0, stream>>>(x_hi, x_lo, Wir, Wiz, Wih,
                                               bir, biz, bih, xg, NGATE, 16);
    gru_scan<<<32, 256, 0, stream>>>(xg, Whr, Whz, Whh, hid,
                                     hs1_hi, hs1_lo, hpk,
                                     out + LOGITS_ELEMS, flags0);
    // layer 2
    gemm_split<0><<<16 * 12, 256, 0, stream>>>(hs1_hi, hs1_lo, Wir + WHE, Wiz + WHE, Wih + WHE,
                                               bir + HDIM, biz + HDIM, bih + HDIM, xg, NGATE, 16);
    gru_scan<<<32, 256, 0, stream>>>(xg, Whr + WHE, Whz + WHE, Whh + WHE, hid + BATCH * HDIM,
                                     hs2_hi, hs2_lo, hpk,
                                     out + LOGITS_ELEMS + BATCH * HDIM, flags1);
    // logits
    gemm_split<1><<<16 * 250, 256, 0, stream>>>(hs2_hi, hs2_lo, Wout, nullptr, nullptr,
                                                bout, nullptr, nullptr, out, VOCAB, 16);
}